// Round 1
// 535.214 us; speedup vs baseline: 1.0052x; 1.0052x over previous
//
#include <hip/hip_runtime.h>

#define B_ 2
#define S_LEN 2048
#define DMODEL 2048
#define NH 16
#define NKVH 4
#define HD 128
#define RLORA 128
#define WINDOW_ 512
#define NGLOBAL 64

typedef __bf16 bf16x8 __attribute__((ext_vector_type(8)));
typedef float f32x4 __attribute__((ext_vector_type(4)));

__device__ __forceinline__ float bf2f(unsigned short h) {
    return __uint_as_float(((unsigned int)h) << 16);
}
__device__ __forceinline__ unsigned short f2bf(float f) {
    unsigned int u = __float_as_uint(f);
    unsigned int r = u + 0x7fffu + ((u >> 16) & 1u);
    return (unsigned short)(r >> 16);
}
__device__ __forceinline__ unsigned int pack2bf(float a, float b) {
    return (unsigned int)f2bf(a) | ((unsigned int)f2bf(b) << 16);
}
__device__ __forceinline__ uint4 load8f(const float* p) {
    float4 f0 = *(const float4*)p;
    float4 f1 = *(const float4*)(p + 4);
    uint4 u;
    u.x = pack2bf(f0.x, f0.y);
    u.y = pack2bf(f0.z, f0.w);
    u.z = pack2bf(f1.x, f1.y);
    u.w = pack2bf(f1.z, f1.w);
    return u;
}

// Async global->LDS, 16 B per lane. LDS dest = wave-uniform base + lane*16.
__device__ __forceinline__ void gld16(const unsigned short* g, unsigned short* l) {
    __builtin_amdgcn_global_load_lds(
        (const __attribute__((address_space(1))) unsigned int*)g,
        (__attribute__((address_space(3))) unsigned int*)l,
        16, 0, 0);
}

// ---------------------------------------------------------------------------
// Batched fp32 -> bf16 conversion over up to 12 tensors. 2048 elems/block.
// ---------------------------------------------------------------------------
struct Conv12 {
    const float* s[12];
    unsigned short* d[12];
    int c[13];
};
__global__ __launch_bounds__(256) void convk(Conv12 a)
{
    int b = blockIdx.x;
    int seg = 0;
    while (b >= a.c[seg + 1]) seg++;
    int off = (b - a.c[seg]) * 2048 + threadIdx.x * 8;
    *(uint4*)(a.d[seg] + off) = load8f(a.s[seg] + off);
}

// ---------------------------------------------------------------------------
// MFMA GEMM, m97-style staging: both operands via global_load_lds width=16.
// All operands bf16 now. OUTF: fp32 out. vtplane: transposed store (V path).
// Layouts (validated r2==r3, passing r5-r9):
//   A-frag: lane holds A[m=lane&15][k=quad*8+j]
//   B-frag: lane holds B[k=quad*8+j][n=lane&15]
//   C/D   : col=lane&15, row=quad*4+reg
// ---------------------------------------------------------------------------
template<int BM, int BN, bool OUTF>
__device__ __forceinline__ void gemm_core(
    const unsigned short* __restrict__ X, int ldx, int m0,
    const unsigned short* __restrict__ W, int ldw, int nrow0,
    const unsigned short* __restrict__ T, int ldt,
    const unsigned short* __restrict__ BL,
    void* __restrict__ Out, int ldo, int ocol0,
    int Kmain,
    unsigned short* __restrict__ vtplane, int s0)
{
    constexpr int BK = 32;
    __shared__ __align__(16) unsigned short As[BM * BK];
    __shared__ __align__(16) unsigned short Bs[BN * BK];
    const int tid = threadIdx.x;
    const int lane = tid & 63;
    const int wid = tid >> 6;
    const int quad = lane >> 4;
    const int l16 = lane & 15;
    const int lr = lane >> 2;
    const int lc8 = (lane & 3) * 8;
    constexpr int TM = BM / 32;
    constexpr int TN = BN / 32;
    const int wm0 = (wid >> 1) * (BM / 2);
    const int wn0 = (wid & 1) * (BN / 2);

    f32x4 acc[TM][TN] = {};

    for (int k0 = 0; k0 < Kmain; k0 += BK) {
        #pragma unroll
        for (int c = 0; c < BM / 64; c++) {
            int chunk = wid * (BM / 64) + c;
            gld16(X + (size_t)(m0 + chunk * 16 + lr) * ldx + k0 + lc8,
                  As + chunk * 512);
        }
        #pragma unroll
        for (int c = 0; c < BN / 64; c++) {
            int chunk = wid * (BN / 64) + c;
            gld16(W + (size_t)(nrow0 + chunk * 16 + lr) * ldw + k0 + lc8,
                  Bs + chunk * 512);
        }
        __syncthreads();
        bf16x8 af[TM], bfr[TN];
        #pragma unroll
        for (int i = 0; i < TM; i++)
            af[i] = *(const bf16x8*)&As[(wm0 + i * 16 + l16) * BK + quad * 8];
        #pragma unroll
        for (int j = 0; j < TN; j++)
            bfr[j] = *(const bf16x8*)&Bs[(wn0 + j * 16 + l16) * BK + quad * 8];
        #pragma unroll
        for (int i = 0; i < TM; i++)
            #pragma unroll
            for (int j = 0; j < TN; j++)
                acc[i][j] = __builtin_amdgcn_mfma_f32_16x16x32_bf16(af[i], bfr[j], acc[i][j], 0, 0, 0);
        __syncthreads();
    }

    if (T != nullptr) {
        for (int k0 = 0; k0 < RLORA; k0 += BK) {
            #pragma unroll
            for (int c = 0; c < BM / 64; c++) {
                int chunk = wid * (BM / 64) + c;
                gld16(T + (size_t)(m0 + chunk * 16 + lr) * ldt + k0 + lc8,
                      As + chunk * 512);
            }
            #pragma unroll
            for (int c = 0; c < BN / 64; c++) {
                int chunk = wid * (BN / 64) + c;
                gld16(BL + (size_t)(nrow0 + chunk * 16 + lr) * RLORA + k0 + lc8,
                      Bs + chunk * 512);
            }
            __syncthreads();
            bf16x8 af[TM], bfr[TN];
            #pragma unroll
            for (int i = 0; i < TM; i++)
                af[i] = *(const bf16x8*)&As[(wm0 + i * 16 + l16) * BK + quad * 8];
            #pragma unroll
            for (int j = 0; j < TN; j++)
                bfr[j] = *(const bf16x8*)&Bs[(wn0 + j * 16 + l16) * BK + quad * 8];
            #pragma unroll
            for (int i = 0; i < TM; i++)
                #pragma unroll
                for (int j = 0; j < TN; j++)
                    acc[i][j] = __builtin_amdgcn_mfma_f32_16x16x32_bf16(af[i], bfr[j], acc[i][j], 0, 0, 0);
            __syncthreads();
        }
    }

    if (vtplane != nullptr) {
        #pragma unroll
        for (int i = 0; i < TM; i++) {
            #pragma unroll
            for (int j = 0; j < TN; j++) {
                const int dd = wn0 + j * 16 + l16;
                const int srow = s0 + wm0 + i * 16 + quad * 4;
                uint2 pk;
                pk.x = pack2bf(acc[i][j][0], acc[i][j][1]);
                pk.y = pack2bf(acc[i][j][2], acc[i][j][3]);
                *(uint2*)(vtplane + (size_t)dd * S_LEN + srow) = pk;
            }
        }
        return;
    }

    #pragma unroll
    for (int i = 0; i < TM; i++) {
        #pragma unroll
        for (int j = 0; j < TN; j++) {
            const int col = ocol0 + wn0 + j * 16 + l16;
            #pragma unroll
            for (int r = 0; r < 4; r++) {
                const size_t row = (size_t)(m0 + wm0 + i * 16 + quad * 4 + r);
                if (OUTF)
                    ((float*)Out)[row * ldo + col] = acc[i][j][r];
                else
                    ((unsigned short*)Out)[row * ldo + col] = f2bf(acc[i][j][r]);
            }
        }
    }
}

template<int BM, int BN, bool OUTF>
__global__ __launch_bounds__(256) void gemm_generic(
    const unsigned short* __restrict__ X, int ldx,
    const unsigned short* __restrict__ W, int ldw,
    const unsigned short* __restrict__ T, int ldt,
    const unsigned short* __restrict__ BL,
    void* __restrict__ Out, int ldo, int Kmain)
{
    gemm_core<BM, BN, OUTF>(X, ldx, blockIdx.x * BM, W, ldw, blockIdx.y * BN,
                            T, ldt, BL, Out, ldo, blockIdx.y * BN, Kmain,
                            nullptr, 0);
}

// Fused QKV over stacked weights; X is pre-converted bf16.
__global__ __launch_bounds__(256) void gemm_qkv(
    const unsigned short* __restrict__ Xb,
    const unsigned short* __restrict__ Wqkv,
    const unsigned short* __restrict__ T,
    const unsigned short* __restrict__ Bqkv,
    unsigned short* __restrict__ Qo, unsigned short* __restrict__ Ko,
    unsigned short* __restrict__ Vt)
{
    const int n0 = blockIdx.y * 128;
    const int m0 = blockIdx.x * 128;
    if (n0 < DMODEL) {
        gemm_core<128, 128, false>(
            Xb, DMODEL, m0, Wqkv, DMODEL, n0, T, 3 * RLORA, Bqkv,
            Qo, DMODEL, n0, DMODEL, nullptr, 0);
    } else if (n0 < DMODEL + 512) {
        gemm_core<128, 128, false>(
            Xb, DMODEL, m0, Wqkv, DMODEL, n0, T + RLORA, 3 * RLORA, Bqkv,
            Ko, 512, n0 - DMODEL, DMODEL, nullptr, 0);
    } else {
        const int ncol = n0 - DMODEL - 512;
        const int b = m0 >> 11;
        const int s0 = m0 & (S_LEN - 1);
        unsigned short* vtplane = Vt + ((size_t)(b * NKVH + (ncol >> 7)) * HD) * S_LEN;
        gemm_core<128, 128, false>(
            Xb, DMODEL, m0, Wqkv, DMODEL, n0, T + 2 * RLORA, 3 * RLORA, Bqkv,
            nullptr, 512, ncol, DMODEL, vtplane, s0);
    }
}

// ---------------------------------------------------------------------------
// RoPE, vectorized (validated r9).
// ---------------------------------------------------------------------------
__global__ __launch_bounds__(256) void rope_vec_k(
    unsigned short* __restrict__ Qb, unsigned short* __restrict__ Kb)
{
    int idx = blockIdx.x * 256 + threadIdx.x;
    const int npq = (B_ * S_LEN) * NH * 16;
    unsigned short* ptr;
    int m, tg;
    if (idx < npq) {
        tg = idx & 15;
        int h = (idx >> 4) & (NH - 1);
        m = idx >> 8;
        ptr = Qb + (size_t)m * (NH * HD) + h * HD + tg * 8;
    } else {
        idx -= npq;
        if (idx >= (B_ * S_LEN) * NKVH * 16) return;
        tg = idx & 15;
        int h = (idx >> 4) & (NKVH - 1);
        m = idx >> 6;
        ptr = Kb + (size_t)m * (NKVH * HD) + h * HD + tg * 8;
    }
    float pos = (float)(m & (S_LEN - 1));
    uint4 u = *(const uint4*)ptr;
    unsigned int w[4] = {u.x, u.y, u.z, u.w};
    #pragma unroll
    for (int j = 0; j < 4; j++) {
        int t = tg * 4 + j;
        float inv_freq = __expf(-(float)t * (13.815510557964274f / 64.0f));
        float ang = pos * inv_freq;
        float c, s;
        __sincosf(ang, &s, &c);
        float xr = __uint_as_float(w[j] << 16);
        float xi = __uint_as_float(w[j] & 0xffff0000u);
        w[j] = pack2bf(xr * c - xi * s, xr * s + xi * c);
    }
    *(uint4*)ptr = make_uint4(w[0], w[1], w[2], w[3]);
}

// ---------------------------------------------------------------------------
// MFMA flash attention v3. Block = (b, kvh, 16-query tile); the 4 waves are
// the 4 heads sharing kvh -> identical K/V addresses (L1 reuse) and identical
// masks (zero divergence). K fragments prefetched one full tile ahead in
// registers; V in two 4-frag groups. Fixed-max softmax (r9-validated).
// O aliases Q safely (Q tile fully read before O write; tiles disjoint).
//
// R0 change: XCD-aware block decode. (b,kvh) group id lives in the LOW 3 bits
// of blockIdx so the dispatcher's round-robin pins one group per XCD -> its
// 1 MB K/V working set is L2-resident (4 MB/XCD) instead of 8 groups
// thrashing. qt in the high bits. Plus s_setprio(1) around MFMA clusters
// (independent-wave regime, m191).
// ---------------------------------------------------------------------------
__global__ __launch_bounds__(256, 4) void attn_mfma(
    const unsigned short* __restrict__ Q,
    const unsigned short* __restrict__ K,
    const unsigned short* __restrict__ Vt,
    unsigned short* __restrict__ O)
{
    __shared__ unsigned short plds[4][16 * 40];
    const int tid = threadIdx.x, lane = tid & 63, wid = tid >> 6;
    const int l16 = lane & 15, quad = lane >> 4;
    const int bid = blockIdx.x;
    const int qt  = bid >> 3;          // high bits: query tile
    const int g   = bid & 7;           // low bits: (b,kvh) -> one group per XCD
    const int kvh = g & 3;
    const int b   = g >> 2;
    const int h   = kvh * 4 + wid;
    const int q0  = qt * 16;

    const unsigned short* qrow = Q + ((size_t)(b * S_LEN + q0 + l16)) * DMODEL + h * HD;
    bf16x8 qf[4];
    #pragma unroll
    for (int c = 0; c < 4; c++)
        qf[c] = *(const bf16x8*)(qrow + c * 32 + quad * 8);

    const unsigned short* Kbase = K + ((size_t)(b * S_LEN)) * (NKVH * HD) + kvh * HD;
    const unsigned short* Vplane = Vt + ((size_t)(b * NKVH + kvh) * HD) * S_LEN;
    unsigned short* pw = &plds[wid][0];

    f32x4 oacc[8] = {};
    f32x4 lrow = {0.f, 0.f, 0.f, 0.f};
    const float c2 = 0.12753102f;   // (1/sqrt(128)) * log2(e)

    const int kthi = (q0 + 15) >> 5;
    int wlo = q0 - (WINDOW_ - 1); if (wlo < 0) wlo = 0;
    const int ktw = wlo >> 5;

    auto nexttile = [&](int t) -> int {
        if (t < ktw) { int u = t + 1; return (u < 2 && u < ktw) ? u : ktw; }
        return t + 1;
    };

    bf16x8 kf0[4], kf1[4];
    auto loadK = [&](int t) {
        const int ktb = t * 32;
        #pragma unroll
        for (int c = 0; c < 4; c++) {
            kf0[c] = *(const bf16x8*)(Kbase + (size_t)(ktb + l16) * (NKVH * HD) + c * 32 + quad * 8);
            kf1[c] = *(const bf16x8*)(Kbase + (size_t)(ktb + 16 + l16) * (NKVH * HD) + c * 32 + quad * 8);
        }
    };

    int kt = 0;
    loadK(kt);

    while (true) {
        const int ktb = kt * 32;
        const bool full = (ktb + 31 <= q0) &&
                          (((q0 + 15) - ktb < WINDOW_) || (ktb + 31 < NGLOBAL));
        // QK^T on prefetched frags
        f32x4 sa0 = {}, sa1 = {};
        __builtin_amdgcn_s_setprio(1);
        #pragma unroll
        for (int c = 0; c < 4; c++) {
            sa0 = __builtin_amdgcn_mfma_f32_16x16x32_bf16(qf[c], kf0[c], sa0, 0, 0, 0);
            sa1 = __builtin_amdgcn_mfma_f32_16x16x32_bf16(qf[c], kf1[c], sa1, 0, 0, 0);
        }
        __builtin_amdgcn_s_setprio(0);
        // prefetch next tile's K (clamped on last iteration)
        const int ktn = nexttile(kt);
        loadK((ktn <= kthi) ? ktn : kt);
        // V group A
        bf16x8 va[4];
        #pragma unroll
        for (int ds = 0; ds < 4; ds++)
            va[ds] = *(const bf16x8*)(Vplane + (size_t)(ds * 16 + l16) * S_LEN + ktb + quad * 8);
        // softmax (fixed max)
        #pragma unroll
        for (int rr = 0; rr < 4; rr++) {
            float p0 = exp2f(sa0[rr] * c2);
            float p1 = exp2f(sa1[rr] * c2);
            if (!full) {
                const int i = q0 + quad * 4 + rr;
                const int j0 = ktb + l16, j1 = j0 + 16;
                bool a0 = (j0 <= i) && ((i - j0 < WINDOW_) || (j0 < NGLOBAL));
                bool a1 = (j1 <= i) && ((i - j1 < WINDOW_) || (j1 < NGLOBAL));
                p0 = a0 ? p0 : 0.f;
                p1 = a1 ? p1 : 0.f;
            }
            lrow[rr] += p0 + p1;
            pw[(quad * 4 + rr) * 40 + l16]      = f2bf(p0);
            pw[(quad * 4 + rr) * 40 + 16 + l16] = f2bf(p1);
        }
        bf16x8 pa = *(const bf16x8*)(pw + l16 * 40 + quad * 8);
        __builtin_amdgcn_s_setprio(1);
        #pragma unroll
        for (int ds = 0; ds < 4; ds++)
            oacc[ds] = __builtin_amdgcn_mfma_f32_16x16x32_bf16(pa, va[ds], oacc[ds], 0, 0, 0);
        __builtin_amdgcn_s_setprio(0);
        // V group B
        bf16x8 vb[4];
        #pragma unroll
        for (int ds = 0; ds < 4; ds++)
            vb[ds] = *(const bf16x8*)(Vplane + (size_t)((ds + 4) * 16 + l16) * S_LEN + ktb + quad * 8);
        __builtin_amdgcn_s_setprio(1);
        #pragma unroll
        for (int ds = 0; ds < 4; ds++)
            oacc[ds + 4] = __builtin_amdgcn_mfma_f32_16x16x32_bf16(pa, vb[ds], oacc[ds + 4], 0, 0, 0);
        __builtin_amdgcn_s_setprio(0);

        if (ktn > kthi) break;
        kt = ktn;
    }

    #pragma unroll
    for (int off = 1; off <= 8; off <<= 1) {
        lrow[0] += __shfl_xor(lrow[0], off);
        lrow[1] += __shfl_xor(lrow[1], off);
        lrow[2] += __shfl_xor(lrow[2], off);
        lrow[3] += __shfl_xor(lrow[3], off);
    }

    #pragma unroll
    for (int rr = 0; rr < 4; rr++) {
        float inv = 1.f / lrow[rr];
        unsigned short* orow = O + ((size_t)(b * S_LEN + q0 + quad * 4 + rr)) * DMODEL + h * HD;
        #pragma unroll
        for (int ds = 0; ds < 8; ds++)
            orow[ds * 16 + l16] = f2bf(oacc[ds][rr] * inv);
    }
}

// ---------------------------------------------------------------------------
extern "C" void kernel_launch(void* const* d_in, const int* in_sizes, int n_in,
                              void* d_out, int out_size, void* d_ws, size_t ws_size,
                              hipStream_t stream)
{
    const float* x    = (const float*)d_in[0];
    const float* wq_w = (const float*)d_in[1];
    const float* wq_a = (const float*)d_in[2];
    const float* wq_b = (const float*)d_in[3];
    const float* wk_w = (const float*)d_in[4];
    const float* wk_a = (const float*)d_in[5];
    const float* wk_b = (const float*)d_in[6];
    const float* wv_w = (const float*)d_in[7];
    const float* wv_a = (const float*)d_in[8];
    const float* wv_b = (const float*)d_in[9];
    const float* wo_w = (const float*)d_in[10];
    const float* wo_a = (const float*)d_in[11];
    const float* wo_b = (const float*)d_in[12];

    char* ws = (char*)d_ws;
    unsigned short* wqkvb = (unsigned short*)(ws);
    unsigned short* apack = (unsigned short*)(ws + 12582912);
    unsigned short* bqkvb = (unsigned short*)(ws + 14155776);
    unsigned short* Tbuf  = (unsigned short*)(ws + 14942208);
    unsigned short* Qbuf  = (unsigned short*)(ws + 18087936);
    unsigned short* Kbuf  = (unsigned short*)(ws + 34865152);
    unsigned short* Vtbuf = (unsigned short*)(ws + 39059456);
    unsigned short* wowb  = (unsigned short*)(ws);
    unsigned short* woab  = (unsigned short*)(ws + 8388608);
    unsigned short* wobb  = (unsigned short*)(ws + 8912896);
    unsigned short* T2buf = Tbuf;
    // x (bf16) lives in d_out's first 16 MB; dead before the final GEMM
    // overwrites d_out with the real fp32 output.
    unsigned short* xb = (unsigned short*)d_out;

    // conv1: x + QKV/LoRA weights -> bf16
    Conv12 c1;
    c1.s[0]  = x;    c1.d[0]  = xb;                   // 4096 blk
    c1.s[1]  = wq_w; c1.d[1]  = wqkvb;                // 2048
    c1.s[2]  = wk_w; c1.d[2]  = wqkvb + 2048 * 2048;  // 512
    c1.s[3]  = wv_w; c1.d[3]  = wqkvb + 2560 * 2048;  // 512
    c1.s[4]  = wq_a; c1.d[4]  = apack;                // 128
    c1.s[5]  = wk_a; c1.d[5]  = apack + 128 * 2048;   // 128
    c1.s[6]  = wv_a; c1.d[6]  = apack + 256 * 2048;   // 128
    c1.s[7]  = wq_b; c1.d[7]  = bqkvb;                // 128
    c1.s[8]  = wk_b; c1.d[8]  = bqkvb + 2048 * 128;   // 32
    c1.s[9]  = wv_b; c1.d[9]  = bqkvb + 2560 * 128;   // 32
    c1.s[10] = wv_b; c1.d[10] = bqkvb + 2560 * 128;
    c1.s[11] = wv_b; c1.d[11] = bqkvb + 2560 * 128;
    int cum1[13] = {0, 4096, 6144, 6656, 7168, 7296, 7424, 7552, 7680, 7712,
                    7744, 7744, 7744};
    for (int i = 0; i < 13; i++) c1.c[i] = cum1[i];
    convk<<<dim3(7744), dim3(256), 0, stream>>>(c1);

    // T = xb @ apack^T
    gemm_generic<128, 128, false><<<dim3(32, 3), dim3(256), 0, stream>>>(
        xb, DMODEL, apack, DMODEL, nullptr, 0, nullptr, Tbuf, 3 * RLORA, DMODEL);

    // Q/K/V (V transposed into Vt)
    gemm_qkv<<<dim3(32, 24), dim3(256), 0, stream>>>(
        xb, wqkvb, Tbuf, bqkvb, Qbuf, Kbuf, Vtbuf);

    // conv2: output-proj weights -> bf16 (over dead wqkvb region)
    Conv12 c2;
    c2.s[0] = wo_w; c2.d[0] = wowb;   // 2048
    c2.s[1] = wo_a; c2.d[1] = woab;   // 128
    c2.s[2] = wo_b; c2.d[2] = wobb;   // 128
    for (int i = 3; i < 12; i++) { c2.s[i] = wo_b; c2.d[i] = wobb; }
    int cum2[13] = {0, 2048, 2176, 2304, 2304, 2304, 2304, 2304, 2304, 2304,
                    2304, 2304, 2304};
    for (int i = 0; i < 13; i++) c2.c[i] = cum2[i];
    convk<<<dim3(2304), dim3(256), 0, stream>>>(c2);

    rope_vec_k<<<dim3(5120), dim3(256), 0, stream>>>(Qbuf, Kbuf);

    attn_mfma<<<dim3(1024), dim3(256), 0, stream>>>(Qbuf, Kbuf, Vtbuf, Qbuf);

    gemm_generic<128, 128, false><<<dim3(32, 1), dim3(256), 0, stream>>>(
        Qbuf, DMODEL, woab, DMODEL, nullptr, 0, nullptr, T2buf, RLORA, DMODEL);

    gemm_generic<128, 128, true><<<dim3(32, 16), dim3(256), 0, stream>>>(
        Qbuf, DMODEL, wowb, DMODEL, T2buf, RLORA, wobb,
        d_out, DMODEL, DMODEL);
}

// Round 2
// 410.790 us; speedup vs baseline: 1.3096x; 1.3029x over previous
//
#include <hip/hip_runtime.h>

#define B_ 2
#define S_LEN 2048
#define DMODEL 2048
#define NH 16
#define NKVH 4
#define HD 128
#define RLORA 128
#define WINDOW_ 512
#define NGLOBAL 64

typedef __bf16 bf16x8 __attribute__((ext_vector_type(8)));
typedef float f32x4 __attribute__((ext_vector_type(4)));

__device__ __forceinline__ float bf2f(unsigned short h) {
    return __uint_as_float(((unsigned int)h) << 16);
}
__device__ __forceinline__ unsigned short f2bf(float f) {
    unsigned int u = __float_as_uint(f);
    unsigned int r = u + 0x7fffu + ((u >> 16) & 1u);
    return (unsigned short)(r >> 16);
}
__device__ __forceinline__ unsigned int pack2bf(float a, float b) {
    return (unsigned int)f2bf(a) | ((unsigned int)f2bf(b) << 16);
}
__device__ __forceinline__ uint4 load8f(const float* p) {
    float4 f0 = *(const float4*)p;
    float4 f1 = *(const float4*)(p + 4);
    uint4 u;
    u.x = pack2bf(f0.x, f0.y);
    u.y = pack2bf(f0.z, f0.w);
    u.z = pack2bf(f1.x, f1.y);
    u.w = pack2bf(f1.z, f1.w);
    return u;
}

// Async global->LDS, 16 B per lane. LDS dest = wave-uniform base + lane*16.
__device__ __forceinline__ void gld16(const unsigned short* g, unsigned short* l) {
    __builtin_amdgcn_global_load_lds(
        (const __attribute__((address_space(1))) unsigned int*)g,
        (__attribute__((address_space(3))) unsigned int*)l,
        16, 0, 0);
}

// ---------------------------------------------------------------------------
// Batched fp32 -> bf16 conversion over up to 12 tensors. 2048 elems/block.
// ---------------------------------------------------------------------------
struct Conv12 {
    const float* s[12];
    unsigned short* d[12];
    int c[13];
};
__global__ __launch_bounds__(256) void convk(Conv12 a)
{
    int b = blockIdx.x;
    int seg = 0;
    while (b >= a.c[seg + 1]) seg++;
    int off = (b - a.c[seg]) * 2048 + threadIdx.x * 8;
    *(uint4*)(a.d[seg] + off) = load8f(a.s[seg] + off);
}

// ---------------------------------------------------------------------------
// MFMA GEMM, m97-style staging: both operands via global_load_lds width=16.
// All operands bf16 now. OUTF: fp32 out. vtplane: transposed store (V path).
// Layouts (validated r2==r3, passing r5-r9):
//   A-frag: lane holds A[m=lane&15][k=quad*8+j]
//   B-frag: lane holds B[k=quad*8+j][n=lane&15]
//   C/D   : col=lane&15, row=quad*4+reg
// ---------------------------------------------------------------------------
template<int BM, int BN, bool OUTF>
__device__ __forceinline__ void gemm_core(
    const unsigned short* __restrict__ X, int ldx, int m0,
    const unsigned short* __restrict__ W, int ldw, int nrow0,
    const unsigned short* __restrict__ T, int ldt,
    const unsigned short* __restrict__ BL,
    void* __restrict__ Out, int ldo, int ocol0,
    int Kmain,
    unsigned short* __restrict__ vtplane, int s0)
{
    constexpr int BK = 32;
    __shared__ __align__(16) unsigned short As[BM * BK];
    __shared__ __align__(16) unsigned short Bs[BN * BK];
    const int tid = threadIdx.x;
    const int lane = tid & 63;
    const int wid = tid >> 6;
    const int quad = lane >> 4;
    const int l16 = lane & 15;
    const int lr = lane >> 2;
    const int lc8 = (lane & 3) * 8;
    constexpr int TM = BM / 32;
    constexpr int TN = BN / 32;
    const int wm0 = (wid >> 1) * (BM / 2);
    const int wn0 = (wid & 1) * (BN / 2);

    f32x4 acc[TM][TN] = {};

    for (int k0 = 0; k0 < Kmain; k0 += BK) {
        #pragma unroll
        for (int c = 0; c < BM / 64; c++) {
            int chunk = wid * (BM / 64) + c;
            gld16(X + (size_t)(m0 + chunk * 16 + lr) * ldx + k0 + lc8,
                  As + chunk * 512);
        }
        #pragma unroll
        for (int c = 0; c < BN / 64; c++) {
            int chunk = wid * (BN / 64) + c;
            gld16(W + (size_t)(nrow0 + chunk * 16 + lr) * ldw + k0 + lc8,
                  Bs + chunk * 512);
        }
        __syncthreads();
        bf16x8 af[TM], bfr[TN];
        #pragma unroll
        for (int i = 0; i < TM; i++)
            af[i] = *(const bf16x8*)&As[(wm0 + i * 16 + l16) * BK + quad * 8];
        #pragma unroll
        for (int j = 0; j < TN; j++)
            bfr[j] = *(const bf16x8*)&Bs[(wn0 + j * 16 + l16) * BK + quad * 8];
        #pragma unroll
        for (int i = 0; i < TM; i++)
            #pragma unroll
            for (int j = 0; j < TN; j++)
                acc[i][j] = __builtin_amdgcn_mfma_f32_16x16x32_bf16(af[i], bfr[j], acc[i][j], 0, 0, 0);
        __syncthreads();
    }

    if (T != nullptr) {
        for (int k0 = 0; k0 < RLORA; k0 += BK) {
            #pragma unroll
            for (int c = 0; c < BM / 64; c++) {
                int chunk = wid * (BM / 64) + c;
                gld16(T + (size_t)(m0 + chunk * 16 + lr) * ldt + k0 + lc8,
                      As + chunk * 512);
            }
            #pragma unroll
            for (int c = 0; c < BN / 64; c++) {
                int chunk = wid * (BN / 64) + c;
                gld16(BL + (size_t)(nrow0 + chunk * 16 + lr) * RLORA + k0 + lc8,
                      Bs + chunk * 512);
            }
            __syncthreads();
            bf16x8 af[TM], bfr[TN];
            #pragma unroll
            for (int i = 0; i < TM; i++)
                af[i] = *(const bf16x8*)&As[(wm0 + i * 16 + l16) * BK + quad * 8];
            #pragma unroll
            for (int j = 0; j < TN; j++)
                bfr[j] = *(const bf16x8*)&Bs[(wn0 + j * 16 + l16) * BK + quad * 8];
            #pragma unroll
            for (int i = 0; i < TM; i++)
                #pragma unroll
                for (int j = 0; j < TN; j++)
                    acc[i][j] = __builtin_amdgcn_mfma_f32_16x16x32_bf16(af[i], bfr[j], acc[i][j], 0, 0, 0);
            __syncthreads();
        }
    }

    if (vtplane != nullptr) {
        #pragma unroll
        for (int i = 0; i < TM; i++) {
            #pragma unroll
            for (int j = 0; j < TN; j++) {
                const int dd = wn0 + j * 16 + l16;
                const int srow = s0 + wm0 + i * 16 + quad * 4;
                uint2 pk;
                pk.x = pack2bf(acc[i][j][0], acc[i][j][1]);
                pk.y = pack2bf(acc[i][j][2], acc[i][j][3]);
                *(uint2*)(vtplane + (size_t)dd * S_LEN + srow) = pk;
            }
        }
        return;
    }

    #pragma unroll
    for (int i = 0; i < TM; i++) {
        #pragma unroll
        for (int j = 0; j < TN; j++) {
            const int col = ocol0 + wn0 + j * 16 + l16;
            #pragma unroll
            for (int r = 0; r < 4; r++) {
                const size_t row = (size_t)(m0 + wm0 + i * 16 + quad * 4 + r);
                if (OUTF)
                    ((float*)Out)[row * ldo + col] = acc[i][j][r];
                else
                    ((unsigned short*)Out)[row * ldo + col] = f2bf(acc[i][j][r]);
            }
        }
    }
}

template<int BM, int BN, bool OUTF>
__global__ __launch_bounds__(256) void gemm_generic(
    const unsigned short* __restrict__ X, int ldx,
    const unsigned short* __restrict__ W, int ldw,
    const unsigned short* __restrict__ T, int ldt,
    const unsigned short* __restrict__ BL,
    void* __restrict__ Out, int ldo, int Kmain)
{
    gemm_core<BM, BN, OUTF>(X, ldx, blockIdx.x * BM, W, ldw, blockIdx.y * BN,
                            T, ldt, BL, Out, ldo, blockIdx.y * BN, Kmain,
                            nullptr, 0);
}

// Fused QKV over stacked weights; X is pre-converted bf16.
__global__ __launch_bounds__(256) void gemm_qkv(
    const unsigned short* __restrict__ Xb,
    const unsigned short* __restrict__ Wqkv,
    const unsigned short* __restrict__ T,
    const unsigned short* __restrict__ Bqkv,
    unsigned short* __restrict__ Qo, unsigned short* __restrict__ Ko,
    unsigned short* __restrict__ Vt)
{
    const int n0 = blockIdx.y * 128;
    const int m0 = blockIdx.x * 128;
    if (n0 < DMODEL) {
        gemm_core<128, 128, false>(
            Xb, DMODEL, m0, Wqkv, DMODEL, n0, T, 3 * RLORA, Bqkv,
            Qo, DMODEL, n0, DMODEL, nullptr, 0);
    } else if (n0 < DMODEL + 512) {
        gemm_core<128, 128, false>(
            Xb, DMODEL, m0, Wqkv, DMODEL, n0, T + RLORA, 3 * RLORA, Bqkv,
            Ko, 512, n0 - DMODEL, DMODEL, nullptr, 0);
    } else {
        const int ncol = n0 - DMODEL - 512;
        const int b = m0 >> 11;
        const int s0 = m0 & (S_LEN - 1);
        unsigned short* vtplane = Vt + ((size_t)(b * NKVH + (ncol >> 7)) * HD) * S_LEN;
        gemm_core<128, 128, false>(
            Xb, DMODEL, m0, Wqkv, DMODEL, n0, T + 2 * RLORA, 3 * RLORA, Bqkv,
            nullptr, 512, ncol, DMODEL, vtplane, s0);
    }
}

// ---------------------------------------------------------------------------
// RoPE, vectorized (validated r9).
// ---------------------------------------------------------------------------
__global__ __launch_bounds__(256) void rope_vec_k(
    unsigned short* __restrict__ Qb, unsigned short* __restrict__ Kb)
{
    int idx = blockIdx.x * 256 + threadIdx.x;
    const int npq = (B_ * S_LEN) * NH * 16;
    unsigned short* ptr;
    int m, tg;
    if (idx < npq) {
        tg = idx & 15;
        int h = (idx >> 4) & (NH - 1);
        m = idx >> 8;
        ptr = Qb + (size_t)m * (NH * HD) + h * HD + tg * 8;
    } else {
        idx -= npq;
        if (idx >= (B_ * S_LEN) * NKVH * 16) return;
        tg = idx & 15;
        int h = (idx >> 4) & (NKVH - 1);
        m = idx >> 6;
        ptr = Kb + (size_t)m * (NKVH * HD) + h * HD + tg * 8;
    }
    float pos = (float)(m & (S_LEN - 1));
    uint4 u = *(const uint4*)ptr;
    unsigned int w[4] = {u.x, u.y, u.z, u.w};
    #pragma unroll
    for (int j = 0; j < 4; j++) {
        int t = tg * 4 + j;
        float inv_freq = __expf(-(float)t * (13.815510557964274f / 64.0f));
        float ang = pos * inv_freq;
        float c, s;
        __sincosf(ang, &s, &c);
        float xr = __uint_as_float(w[j] << 16);
        float xi = __uint_as_float(w[j] & 0xffff0000u);
        w[j] = pack2bf(xr * c - xi * s, xr * s + xi * c);
    }
    *(uint4*)ptr = make_uint4(w[0], w[1], w[2], w[3]);
}

// ---------------------------------------------------------------------------
// MFMA flash attention v4 (R1): LDS-staged K/V shared by the whole block.
//
// R0->R1 post-mortem: FETCH_SIZE dropped 158->20.5 MB (K/V L2-resident) but
// dur was unchanged -> NOT fill-latency-bound. Bottleneck: per-wave strided
// 16B global loads touch 16 cache lines each; 256 L1 line-transactions per
// wave-iter, x4 redundant across the block's waves, all L1 misses ->
// TCP request-rate wall (insensitive to where the fill comes from).
//
// New structure:
//   Block = (b, kvh, 32-query chunk); grid 512 (desc. length, XCD low bits).
//   Per k-tile (32 keys): K (32x128, 8KB) + V^T (128x32, 8KB) staged into
//   LDS via global_load_lds w=16, double-buffered, ONE barrier/iter.
//   Swizzle: LDS stays linear; the per-lane GLOBAL source is pre-swizzled
//   (m173) with K: byte^=((key&15)<<4), V: byte^=((d&3)<<4); ds_read_b128
//   applies the same XOR -> conflict floor.
//   Each wave = 1 head x 32 queries (2 subtiles) -> K/V frags reused 2x.
//   Softmax: fixed-max (validated r9); P via per-wave LDS (40-elem rows).
//   O aliases Q safely (block reads its own Q rows in prologue only).
// ---------------------------------------------------------------------------
__global__ __launch_bounds__(256, 2) void attn_mfma(
    const unsigned short* __restrict__ Q,
    const unsigned short* __restrict__ K,
    const unsigned short* __restrict__ Vt,
    unsigned short* __restrict__ O)
{
    __shared__ __align__(16) unsigned short kvbuf[2][8192]; // [buf]: K 0..4095, V 4096..8191 (shorts)
    __shared__ unsigned short plds[4][32 * 40];
    const int tid = threadIdx.x, lane = tid & 63, wid = tid >> 6;
    const int l16 = lane & 15, quad = lane >> 4;
    const int bid = blockIdx.x;
    const int g   = bid & 7;            // (b,kvh) in low bits -> XCD locality
    const int kvh = g & 3;
    const int b   = g >> 2;
    const int qt  = 63 - (bid >> 3);    // descending: longest blocks first
    const int q0  = qt * 32;
    const int h   = kvh * 4 + wid;

    // ---- Q fragments: rows q0+l16 (sub0), q0+16+l16 (sub1) ----
    const unsigned short* qrow0 = Q + ((size_t)(b * S_LEN + q0 + l16)) * DMODEL + h * HD;
    bf16x8 qf0[4], qf1[4];
    #pragma unroll
    for (int c = 0; c < 4; c++) {
        qf0[c] = *(const bf16x8*)(qrow0 + c * 32 + quad * 8);
        qf1[c] = *(const bf16x8*)(qrow0 + (size_t)16 * DMODEL + c * 32 + quad * 8);
    }

    const unsigned short* Kbase  = K + ((size_t)(b * S_LEN)) * (NKVH * HD) + kvh * HD;
    const unsigned short* Vplane = Vt + ((size_t)(b * NKVH + kvh) * HD) * S_LEN;
    unsigned short* pw = &plds[wid][0];

    // ---- staging source precompute (per thread, 2 chunks of 1KB each) ----
    // K: LDS linear [key][dim] rows of 256B; src byte ^= ((key&15)<<4).
    // V: LDS linear [d][key] rows of 64B;   src byte ^= ((d&3)<<4).
    const unsigned short* Ksrc[2];
    const unsigned short* Vsrc[2];
    #pragma unroll
    for (int c = 0; c < 2; c++) {
        const int o = wid * 2048 + c * 1024 + lane * 16;     // byte offset in 8KB tile
        const int kkey = o >> 8;
        const int kdim = (o & 255) ^ ((kkey & 15) << 4);
        Ksrc[c] = Kbase + (size_t)kkey * (NKVH * HD) + (kdim >> 1);
        const int vd = o >> 6;
        const int vkb = (o & 63) ^ ((vd & 3) << 4);
        Vsrc[c] = Vplane + (size_t)vd * S_LEN + (vkb >> 1);
    }

    f32x4 oacc0[8] = {}, oacc1[8] = {};
    f32x4 lrow0 = {0.f, 0.f, 0.f, 0.f}, lrow1 = {0.f, 0.f, 0.f, 0.f};
    const float c2 = 0.12753102f;   // (1/sqrt(128)) * log2(e)

    const int kthi = (q0 + 31) >> 5;
    int wlo = q0 - (WINDOW_ - 1); if (wlo < 0) wlo = 0;
    const int ktw = wlo >> 5;

    auto nexttile = [&](int t) -> int {
        if (t < ktw) { int u = t + 1; return (u < 2 && u < ktw) ? u : ktw; }
        return t + 1;
    };

    auto stage = [&](int buf, int ktb) {
        #pragma unroll
        for (int c = 0; c < 2; c++) {
            gld16(Ksrc[c] + (size_t)ktb * (NKVH * HD),
                  &kvbuf[buf][wid * 1024 + c * 512]);
            gld16(Vsrc[c] + ktb,
                  &kvbuf[buf][4096 + wid * 1024 + c * 512]);
        }
    };

    int kt = 0;
    stage(0, 0);
    __syncthreads();
    int cur = 0;

    while (true) {
        const int ktb = kt * 32;
        const int ktn = nexttile(kt);
        const bool last = (ktn > kthi);
        if (!last) stage(cur ^ 1, ktn * 32);

        const unsigned short* kb  = kvbuf[cur];
        const unsigned short* vbp = kvbuf[cur] + 4096;

        // K fragments from LDS (swizzled read): rows l16 / l16+16
        bf16x8 kf0[4], kf1[4];
        #pragma unroll
        for (int c = 0; c < 4; c++) {
            const int koff = (l16 * 256 + ((c * 64 + quad * 16) ^ (l16 << 4))) >> 1;
            kf0[c] = *(const bf16x8*)&kb[koff];
            kf1[c] = *(const bf16x8*)&kb[koff + 2048];
        }

        // QK^T for both subtiles
        f32x4 s00 = {}, s01 = {}, s10 = {}, s11 = {};
        __builtin_amdgcn_s_setprio(1);
        #pragma unroll
        for (int c = 0; c < 4; c++) {
            s00 = __builtin_amdgcn_mfma_f32_16x16x32_bf16(qf0[c], kf0[c], s00, 0, 0, 0);
            s01 = __builtin_amdgcn_mfma_f32_16x16x32_bf16(qf0[c], kf1[c], s01, 0, 0, 0);
            s10 = __builtin_amdgcn_mfma_f32_16x16x32_bf16(qf1[c], kf0[c], s10, 0, 0, 0);
            s11 = __builtin_amdgcn_mfma_f32_16x16x32_bf16(qf1[c], kf1[c], s11, 0, 0, 0);
        }
        __builtin_amdgcn_s_setprio(0);

        // softmax per subtile -> P rows in per-wave LDS
        #pragma unroll
        for (int s = 0; s < 2; s++) {
            const f32x4 sa0 = s ? s10 : s00;
            const f32x4 sa1 = s ? s11 : s01;
            const int qs = q0 + s * 16;
            const bool full = (ktb + 31 <= qs) &&
                              (((qs + 15) - ktb < WINDOW_) || (ktb + 31 < NGLOBAL));
            f32x4& lr = s ? lrow1 : lrow0;
            #pragma unroll
            for (int rr = 0; rr < 4; rr++) {
                float p0 = exp2f(sa0[rr] * c2);
                float p1 = exp2f(sa1[rr] * c2);
                if (!full) {
                    const int i = qs + quad * 4 + rr;
                    const int j0 = ktb + l16, j1 = j0 + 16;
                    bool a0 = (j0 <= i) && ((i - j0 < WINDOW_) || (j0 < NGLOBAL));
                    bool a1 = (j1 <= i) && ((i - j1 < WINDOW_) || (j1 < NGLOBAL));
                    p0 = a0 ? p0 : 0.f;
                    p1 = a1 ? p1 : 0.f;
                }
                lr[rr] += p0 + p1;
                pw[(s * 16 + quad * 4 + rr) * 40 + l16]      = f2bf(p0);
                pw[(s * 16 + quad * 4 + rr) * 40 + 16 + l16] = f2bf(p1);
            }
        }
        bf16x8 pa0 = *(const bf16x8*)(pw + l16 * 40 + quad * 8);
        bf16x8 pa1 = *(const bf16x8*)(pw + (16 + l16) * 40 + quad * 8);

        // V group A (d 0..63) from LDS
        {
            bf16x8 va[4];
            #pragma unroll
            for (int ds = 0; ds < 4; ds++) {
                const int d = ds * 16 + l16;
                va[ds] = *(const bf16x8*)&vbp[(d * 64 + ((quad * 16) ^ ((l16 & 3) << 4))) >> 1];
            }
            __builtin_amdgcn_s_setprio(1);
            #pragma unroll
            for (int ds = 0; ds < 4; ds++) {
                oacc0[ds] = __builtin_amdgcn_mfma_f32_16x16x32_bf16(pa0, va[ds], oacc0[ds], 0, 0, 0);
                oacc1[ds] = __builtin_amdgcn_mfma_f32_16x16x32_bf16(pa1, va[ds], oacc1[ds], 0, 0, 0);
            }
            __builtin_amdgcn_s_setprio(0);
        }
        // V group B (d 64..127)
        {
            bf16x8 vb[4];
            #pragma unroll
            for (int ds = 0; ds < 4; ds++) {
                const int d = (ds + 4) * 16 + l16;
                vb[ds] = *(const bf16x8*)&vbp[(d * 64 + ((quad * 16) ^ ((l16 & 3) << 4))) >> 1];
            }
            __builtin_amdgcn_s_setprio(1);
            #pragma unroll
            for (int ds = 0; ds < 4; ds++) {
                oacc0[ds + 4] = __builtin_amdgcn_mfma_f32_16x16x32_bf16(pa0, vb[ds], oacc0[ds + 4], 0, 0, 0);
                oacc1[ds + 4] = __builtin_amdgcn_mfma_f32_16x16x32_bf16(pa1, vb[ds], oacc1[ds + 4], 0, 0, 0);
            }
            __builtin_amdgcn_s_setprio(0);
        }

        if (last) break;
        __syncthreads();
        cur ^= 1;
        kt = ktn;
    }

    #pragma unroll
    for (int off = 1; off <= 8; off <<= 1) {
        #pragma unroll
        for (int rr = 0; rr < 4; rr++) {
            lrow0[rr] += __shfl_xor(lrow0[rr], off);
            lrow1[rr] += __shfl_xor(lrow1[rr], off);
        }
    }

    #pragma unroll
    for (int s = 0; s < 2; s++) {
        const f32x4& lr = s ? lrow1 : lrow0;
        #pragma unroll
        for (int rr = 0; rr < 4; rr++) {
            float inv = 1.f / lr[rr];
            unsigned short* orow = O + ((size_t)(b * S_LEN + q0 + s * 16 + quad * 4 + rr)) * DMODEL + h * HD;
            #pragma unroll
            for (int ds = 0; ds < 8; ds++) {
                float v = s ? oacc1[ds][rr] : oacc0[ds][rr];
                orow[ds * 16 + l16] = f2bf(v * inv);
            }
        }
    }
}

// ---------------------------------------------------------------------------
extern "C" void kernel_launch(void* const* d_in, const int* in_sizes, int n_in,
                              void* d_out, int out_size, void* d_ws, size_t ws_size,
                              hipStream_t stream)
{
    const float* x    = (const float*)d_in[0];
    const float* wq_w = (const float*)d_in[1];
    const float* wq_a = (const float*)d_in[2];
    const float* wq_b = (const float*)d_in[3];
    const float* wk_w = (const float*)d_in[4];
    const float* wk_a = (const float*)d_in[5];
    const float* wk_b = (const float*)d_in[6];
    const float* wv_w = (const float*)d_in[7];
    const float* wv_a = (const float*)d_in[8];
    const float* wv_b = (const float*)d_in[9];
    const float* wo_w = (const float*)d_in[10];
    const float* wo_a = (const float*)d_in[11];
    const float* wo_b = (const float*)d_in[12];

    char* ws = (char*)d_ws;
    unsigned short* wqkvb = (unsigned short*)(ws);
    unsigned short* apack = (unsigned short*)(ws + 12582912);
    unsigned short* bqkvb = (unsigned short*)(ws + 14155776);
    unsigned short* Tbuf  = (unsigned short*)(ws + 14942208);
    unsigned short* Qbuf  = (unsigned short*)(ws + 18087936);
    unsigned short* Kbuf  = (unsigned short*)(ws + 34865152);
    unsigned short* Vtbuf = (unsigned short*)(ws + 39059456);
    unsigned short* wowb  = (unsigned short*)(ws);
    unsigned short* woab  = (unsigned short*)(ws + 8388608);
    unsigned short* wobb  = (unsigned short*)(ws + 8912896);
    unsigned short* T2buf = Tbuf;
    // x (bf16) lives in d_out's first 16 MB; dead before the final GEMM
    // overwrites d_out with the real fp32 output.
    unsigned short* xb = (unsigned short*)d_out;

    // conv1: x + QKV/LoRA weights -> bf16
    Conv12 c1;
    c1.s[0]  = x;    c1.d[0]  = xb;                   // 4096 blk
    c1.s[1]  = wq_w; c1.d[1]  = wqkvb;                // 2048
    c1.s[2]  = wk_w; c1.d[2]  = wqkvb + 2048 * 2048;  // 512
    c1.s[3]  = wv_w; c1.d[3]  = wqkvb + 2560 * 2048;  // 512
    c1.s[4]  = wq_a; c1.d[4]  = apack;                // 128
    c1.s[5]  = wk_a; c1.d[5]  = apack + 128 * 2048;   // 128
    c1.s[6]  = wv_a; c1.d[6]  = apack + 256 * 2048;   // 128
    c1.s[7]  = wq_b; c1.d[7]  = bqkvb;                // 128
    c1.s[8]  = wk_b; c1.d[8]  = bqkvb + 2048 * 128;   // 32
    c1.s[9]  = wv_b; c1.d[9]  = bqkvb + 2560 * 128;   // 32
    c1.s[10] = wv_b; c1.d[10] = bqkvb + 2560 * 128;
    c1.s[11] = wv_b; c1.d[11] = bqkvb + 2560 * 128;
    int cum1[13] = {0, 4096, 6144, 6656, 7168, 7296, 7424, 7552, 7680, 7712,
                    7744, 7744, 7744};
    for (int i = 0; i < 13; i++) c1.c[i] = cum1[i];
    convk<<<dim3(7744), dim3(256), 0, stream>>>(c1);

    // T = xb @ apack^T
    gemm_generic<128, 128, false><<<dim3(32, 3), dim3(256), 0, stream>>>(
        xb, DMODEL, apack, DMODEL, nullptr, 0, nullptr, Tbuf, 3 * RLORA, DMODEL);

    // Q/K/V (V transposed into Vt)
    gemm_qkv<<<dim3(32, 24), dim3(256), 0, stream>>>(
        xb, wqkvb, Tbuf, bqkvb, Qbuf, Kbuf, Vtbuf);

    // conv2: output-proj weights -> bf16 (over dead wqkvb region)
    Conv12 c2;
    c2.s[0] = wo_w; c2.d[0] = wowb;   // 2048
    c2.s[1] = wo_a; c2.d[1] = woab;   // 128
    c2.s[2] = wo_b; c2.d[2] = wobb;   // 128
    for (int i = 3; i < 12; i++) { c2.s[i] = wo_b; c2.d[i] = wobb; }
    int cum2[13] = {0, 2048, 2176, 2304, 2304, 2304, 2304, 2304, 2304, 2304,
                    2304, 2304, 2304};
    for (int i = 0; i < 13; i++) c2.c[i] = cum2[i];
    convk<<<dim3(2304), dim3(256), 0, stream>>>(c2);

    rope_vec_k<<<dim3(5120), dim3(256), 0, stream>>>(Qbuf, Kbuf);

    attn_mfma<<<dim3(512), dim3(256), 0, stream>>>(Qbuf, Kbuf, Vtbuf, Qbuf);

    gemm_generic<128, 128, false><<<dim3(32, 1), dim3(256), 0, stream>>>(
        Qbuf, DMODEL, woab, DMODEL, nullptr, 0, nullptr, T2buf, RLORA, DMODEL);

    gemm_generic<128, 128, true><<<dim3(32, 16), dim3(256), 0, stream>>>(
        Qbuf, DMODEL, wowb, DMODEL, T2buf, RLORA, wobb,
        d_out, DMODEL, DMODEL);
}